// Round 1
// baseline (41.219 us; speedup 1.0000x reference)
//
#include <hip/hip_runtime.h>

#define BB 32
#define NN 2048
#define WW 64
#define CC 1024
#define NTAP 17
#define SCAL_STRIDE 96
#define EPSF 1e-8f

// ws layout (floats), per-batch stride SCAL_STRIDE:
//   [0..63]  k (tanh of projection)
//   [64]     beta (softplus)
//   [65]     gate (sigmoid)
//   [66..82] wd[17] tap weights, pre-multiplied by 1/(S+eps)

__device__ __forceinline__ unsigned f2sort(float f) {
    unsigned u = __float_as_uint(f);
    return u ^ ((u >> 31) ? 0xFFFFFFFFu : 0x80000000u);
}
__device__ __forceinline__ float sort2f(unsigned u) {
    u ^= (u >> 31) ? 0x80000000u : 0xFFFFFFFFu;
    return __uint_as_float(u);
}

// ---------------------------------------------------------------------------
// K1: blocks 0..31  -> per-batch sort + allocation weights (d_out slot 3)
//     blocks 32..63 -> per-batch controller projections -> scal ws
// ---------------------------------------------------------------------------
__global__ __launch_bounds__(1024) void k_front(
    const float* __restrict__ co, const float* __restrict__ usage,
    const float* __restrict__ Wk, const float* __restrict__ bk,
    const float* __restrict__ Wb, const float* __restrict__ bb,
    const float* __restrict__ Ws, const float* __restrict__ bs,
    const float* __restrict__ Wg, const float* __restrict__ bg,
    float* __restrict__ scal, float* __restrict__ alloc_out)
{
    __shared__ unsigned long long keys[NN];   // sort path (16 KB)
    __shared__ float co_s[CC];                // dots path (4 KB)
    __shared__ float logits[80];
    __shared__ float wave_tot[16];
    const int tid = threadIdx.x;

    if (blockIdx.x < BB) {
        // ================= sort + allocation =================
        const int b = blockIdx.x;
        for (int i = tid; i < NN; i += 1024) {
            float u = usage[(size_t)b * NN + i];
            keys[i] = ((unsigned long long)f2sort(u) << 32) | (unsigned)i;
        }
        __syncthreads();
        // bitonic sort, ascending, stable via index in low bits
        for (unsigned k = 2; k <= NN; k <<= 1) {
            for (unsigned j = k >> 1; j > 0; j >>= 1) {
                unsigned i = (tid << 1) - (tid & (j - 1));
                unsigned p = i + j;
                unsigned long long a = keys[i], c2 = keys[p];
                if ((a > c2) == ((i & k) == 0)) { keys[i] = c2; keys[p] = a; }
                __syncthreads();
            }
        }
        // each thread owns sorted elements 2*tid, 2*tid+1
        unsigned long long e0 = keys[2 * tid], e1 = keys[2 * tid + 1];
        float x0 = 1.0f - sort2f((unsigned)(e0 >> 32));
        float x1 = 1.0f - sort2f((unsigned)(e1 >> 32));
        float own = x0 * x1;
        // inclusive product scan within wave
        float v = own;
        int lane = tid & 63;
        for (int off = 1; off < 64; off <<= 1) {
            float t = __shfl_up(v, off);
            if (lane >= off) v *= t;
        }
        if (lane == 63) wave_tot[tid >> 6] = v;
        __syncthreads();
        if (tid < 16) {
            float w = wave_tot[tid];
            for (int off = 1; off < 16; off <<= 1) {
                float t = __shfl_up(w, off);
                if (tid >= off) w *= t;
            }
            wave_tot[tid] = w;   // inclusive scan of wave totals
        }
        __syncthreads();
        float prefix = (tid >= 64) ? wave_tot[(tid >> 6) - 1] : 1.0f;
        float excl = __shfl_up(v, 1);
        if (lane == 0) excl = 1.0f;
        excl *= prefix;                    // product of all elements before 2*tid
        float c0 = excl * x0;              // cumprod at sorted pos 2*tid
        float c1 = c0 * x1;                // cumprod at sorted pos 2*tid+1
        float* ao = alloc_out + (size_t)b * NN;
        ao[(unsigned)(e0 & 0xFFFFFFFFu)] = c0;
        ao[(unsigned)(e1 & 0xFFFFFFFFu)] = c1;
    } else {
        // ================= controller projections =================
        const int b = blockIdx.x - BB;
        for (int i = tid; i < CC; i += 1024) co_s[i] = co[(size_t)b * CC + i];
        __syncthreads();
        const int wave = tid >> 6, lane = tid & 63;
        for (int o = wave; o < 69; o += 16) {
            const float* row; float bias;
            if (o < 64)      { row = Wk + (size_t)o * CC; bias = bk[o]; }
            else if (o == 64){ row = Wb;                  bias = bb[0]; }
            else if (o < 68) { row = Ws + (size_t)(o - 65) * CC; bias = bs[o - 65]; }
            else             { row = Wg;                  bias = bg[0]; }
            float s = 0.f;
            for (int c = lane; c < CC; c += 64) s = fmaf(co_s[c], row[c], s);
            #pragma unroll
            for (int off = 32; off; off >>= 1) s += __shfl_xor(s, off);
            if (lane == 0) logits[o] = s + bias;
        }
        __syncthreads();
        float* sb = scal + (size_t)b * SCAL_STRIDE;
        if (tid < 64) {
            sb[tid] = tanhf(logits[tid]);
        } else if (tid == 64) {
            float x = logits[64];                       // beta = softplus
            sb[64] = (x > 20.f) ? x : log1pf(__expf(x));
        } else if (tid == 65) {
            float x = logits[68];                       // gate = sigmoid
            sb[65] = 1.f / (1.f + __expf(-x));
        } else if (tid == 66) {
            float s0 = logits[65], s1 = logits[66], s2 = logits[67];
            float m = fmaxf(s0, fmaxf(s1, s2));
            float ex0 = __expf(s0 - m), ex1 = __expf(s1 - m), ex2 = __expf(s2 - m);
            float inv = 1.f / (ex0 + ex1 + ex2);
            float sc = (ex2 - ex0) * inv;               // -shift0 + shift2
            float den = 2.f * sc * sc + EPSF;
            float wd[NTAP]; float S = 0.f;
            #pragma unroll
            for (int d = 0; d < NTAP; d++) {
                wd[d] = __expf(-(float)(d * d) / den);
                S += wd[d];
            }
            float invS = 1.f / (S + EPSF);
            #pragma unroll
            for (int d = 0; d < NTAP; d++) sb[66 + d] = wd[d] * invS;
        }
    }
}

// ---------------------------------------------------------------------------
// K2: sim[b,n] = memory[b,n,:]·k[b,:]  -> staged into d_out slot 0
//     grid 256 blocks x 256 threads; 16 lanes per row, float4 loads
// ---------------------------------------------------------------------------
__global__ __launch_bounds__(256) void k_sim(
    const float* __restrict__ mem, const float* __restrict__ scal,
    float* __restrict__ sim)
{
    const int b = blockIdx.x >> 3, seg = blockIdx.x & 7;
    const int tid = threadIdx.x;
    const int lane16 = tid & 15;
    const int group = tid >> 4;   // 0..15
    const float4 kv = *reinterpret_cast<const float4*>(
        scal + (size_t)b * SCAL_STRIDE + lane16 * 4);
    #pragma unroll 4
    for (int it = 0; it < 16; it++) {
        int row = seg * 256 + it * 16 + group;
        const float4 m4 = *reinterpret_cast<const float4*>(
            mem + ((size_t)b * NN + row) * WW + lane16 * 4);
        float s = m4.x * kv.x + m4.y * kv.y + m4.z * kv.z + m4.w * kv.w;
        s += __shfl_xor(s, 1); s += __shfl_xor(s, 2);
        s += __shfl_xor(s, 4); s += __shfl_xor(s, 8);
        if (lane16 == 0) sim[(size_t)b * NN + row] = s;
    }
}

// ---------------------------------------------------------------------------
// K3: per-batch softmax(content) + 17-tap directional + combine
//     reads sim from slot0, alloc from slot3; writes slots 0,1,2
// ---------------------------------------------------------------------------
__global__ __launch_bounds__(1024) void k_post(
    const float* __restrict__ rdw, const float* __restrict__ scal,
    float* out)
{
    __shared__ float r_s[NN];
    __shared__ float wd_s[NTAP];
    __shared__ float red[16];
    __shared__ float bcast[2];
    const int b = blockIdx.x, tid = threadIdx.x;
    const float* sb = scal + (size_t)b * SCAL_STRIDE;
    const float beta = sb[64], gate = sb[65];
    if (tid < NTAP) wd_s[tid] = sb[66 + tid];
    r_s[tid]        = rdw[(size_t)b * NN + tid];
    r_s[tid + 1024] = rdw[(size_t)b * NN + tid + 1024];

    float s0 = out[(size_t)b * NN + tid] * beta;          // sim staged in slot0
    float s1 = out[(size_t)b * NN + tid + 1024] * beta;

    // block max
    float m = fmaxf(s0, s1);
    #pragma unroll
    for (int off = 32; off; off >>= 1) m = fmaxf(m, __shfl_xor(m, off));
    if ((tid & 63) == 0) red[tid >> 6] = m;
    __syncthreads();
    if (tid < 16) {
        float v = red[tid];
        v = fmaxf(v, __shfl_xor(v, 1)); v = fmaxf(v, __shfl_xor(v, 2));
        v = fmaxf(v, __shfl_xor(v, 4)); v = fmaxf(v, __shfl_xor(v, 8));
        if (tid == 0) bcast[0] = v;
    }
    __syncthreads();
    m = bcast[0];
    float e0 = __expf(s0 - m), e1 = __expf(s1 - m);
    float ssum = e0 + e1;
    #pragma unroll
    for (int off = 32; off; off >>= 1) ssum += __shfl_xor(ssum, off);
    if ((tid & 63) == 0) red[tid >> 6] = ssum;
    __syncthreads();
    if (tid < 16) {
        float v = red[tid];
        v += __shfl_xor(v, 1); v += __shfl_xor(v, 2);
        v += __shfl_xor(v, 4); v += __shfl_xor(v, 8);
        if (tid == 0) bcast[1] = v;
    }
    __syncthreads();
    const float inv = 1.f / bcast[1];
    const float c0 = e0 * inv, c1 = e1 * inv;
    out[(size_t)BB * NN + (size_t)b * NN + tid]        = c0;   // content
    out[(size_t)BB * NN + (size_t)b * NN + tid + 1024] = c1;

    // directional: dw[m] = sum_d wd[d] * r[(m + 1024 + d) & 2047]
    float dw0 = 0.f, dw1 = 0.f;
    #pragma unroll
    for (int d = 0; d < NTAP; d++) {
        float w = wd_s[d];
        dw0 = fmaf(w, r_s[(tid + 1024 + d) & (NN - 1)], dw0);
        dw1 = fmaf(w, r_s[(tid + d) & (NN - 1)], dw1);
    }
    out[2 * (size_t)BB * NN + (size_t)b * NN + tid]        = dw0;
    out[2 * (size_t)BB * NN + (size_t)b * NN + tid + 1024] = dw1;

    const float a0 = out[3 * (size_t)BB * NN + (size_t)b * NN + tid];
    const float a1 = out[3 * (size_t)BB * NN + (size_t)b * NN + tid + 1024];
    out[(size_t)b * NN + tid]        = gate * (0.5f * c0 + 0.5f * dw0 * a0);
    out[(size_t)b * NN + tid + 1024] = gate * (0.5f * c1 + 0.5f * dw1 * a1);
}

extern "C" void kernel_launch(void* const* d_in, const int* in_sizes, int n_in,
                              void* d_out, int out_size, void* d_ws, size_t ws_size,
                              hipStream_t stream) {
    const float* co    = (const float*)d_in[0];
    const float* rdw   = (const float*)d_in[1];
    const float* mem   = (const float*)d_in[3];
    const float* usage = (const float*)d_in[4];
    const float* Wk    = (const float*)d_in[5];
    const float* bk    = (const float*)d_in[6];
    const float* Wb    = (const float*)d_in[7];
    const float* bb    = (const float*)d_in[8];
    const float* Ws_   = (const float*)d_in[9];
    const float* bs    = (const float*)d_in[10];
    const float* Wg    = (const float*)d_in[11];
    const float* bg    = (const float*)d_in[12];
    float* out  = (float*)d_out;
    float* scal = (float*)d_ws;

    hipLaunchKernelGGL(k_front, dim3(2 * BB), dim3(1024), 0, stream,
                       co, usage, Wk, bk, Wb, bb, Ws_, bs, Wg, bg,
                       scal, out + 3 * (size_t)BB * NN);
    hipLaunchKernelGGL(k_sim, dim3(256), dim3(256), 0, stream,
                       mem, scal, out /* slot0 = sim staging */);
    hipLaunchKernelGGL(k_post, dim3(BB), dim3(1024), 0, stream,
                       rdw, scal, out);
}